// Round 5
// baseline (262.303 us; speedup 1.0000x reference)
//
#include <hip/hip_runtime.h>

typedef unsigned short u16;
typedef unsigned int   u32;
typedef float  f32x4  __attribute__((ext_vector_type(4)));
typedef __bf16 bf16x8 __attribute__((ext_vector_type(8)));
typedef __bf16 bf16x4 __attribute__((ext_vector_type(4)));
typedef short  s16x4  __attribute__((ext_vector_type(4)));
typedef unsigned short u16x8 __attribute__((ext_vector_type(8)));
typedef unsigned int   u32x4 __attribute__((ext_vector_type(4)));

// fp32 -> bf16 round-to-nearest-even
__device__ __forceinline__ u16 f2bf(float f) {
  u32 u = __builtin_bit_cast(u32, f);
  u = (u + 0x7fffu + ((u >> 16) & 1u)) >> 16;
  return (u16)u;
}

// async global->LDS, 16B per lane; LDS dest is wave-uniform base (HW adds lane*16)
__device__ __forceinline__ void gload_lds16(const void* g, void* l) {
  __builtin_amdgcn_global_load_lds(
      (const __attribute__((address_space(1))) void*)g,
      (__attribute__((address_space(3))) void*)l, 16, 0, 0);
}

#define LGKM0()  asm volatile("s_waitcnt lgkmcnt(0)" ::: "memory")
#define VMCNT6() asm volatile("s_waitcnt vmcnt(6)" ::: "memory")
#define VMCNT0() asm volatile("s_waitcnt vmcnt(0)" ::: "memory")

// ---------------------------------------------------------------------------
// fp32 -> bf16 elementwise (8 elems/thread)
__global__ __launch_bounds__(256) void conv_f32_bf16(
    const float* __restrict__ in, u16* __restrict__ out, int n8) {
  int i = blockIdx.x * 256 + threadIdx.x;
  if (i >= n8) return;
  const float4* p = (const float4*)in;
  float4 a = p[2 * i], b = p[2 * i + 1];
  u16x8 r;
  r[0] = f2bf(a.x); r[1] = f2bf(a.y); r[2] = f2bf(a.z); r[3] = f2bf(a.w);
  r[4] = f2bf(b.x); r[5] = f2bf(b.y); r[6] = f2bf(b.z); r[7] = f2bf(b.w);
  ((u16x8*)out)[i] = r;
}

// fp32 [K][N] -> bf16 [N][K] transpose (64x64 tiles via LDS)
__global__ __launch_bounds__(256) void conv_transpose(
    const float* __restrict__ in, u16* __restrict__ out, int K, int N) {
  __shared__ float tile[64][65];
  int nb = N >> 6;
  int tk = blockIdx.x / nb, tn = blockIdx.x % nb;
  int t = threadIdx.x;
  int kl = t >> 4, n4 = (t & 15) * 4;
#pragma unroll
  for (int i = 0; i < 4; ++i) {
    int k = kl + 16 * i;
    float4 v = *(const float4*)(in + (size_t)(tk * 64 + k) * N + tn * 64 + n4);
    tile[k][n4] = v.x; tile[k][n4 + 1] = v.y; tile[k][n4 + 2] = v.z; tile[k][n4 + 3] = v.w;
  }
  __syncthreads();
  int nl = t >> 4, k4 = (t & 15) * 4;
#pragma unroll
  for (int i = 0; i < 4; ++i) {
    int n = nl + 16 * i;
    ushort4 o;
    o.x = f2bf(tile[k4 + 0][n]); o.y = f2bf(tile[k4 + 1][n]);
    o.z = f2bf(tile[k4 + 2][n]); o.w = f2bf(tile[k4 + 3][n]);
    *(ushort4*)(out + (size_t)(tn * 64 + n) * K + tk * 64 + k4) = o;
  }
}

// ---------------------------------------------------------------------------
// 8-phase-style counted-vmcnt GEMM: C[M][N] = A[M][K]*Bt[N][K]^T + bias.
// BM=256, BN=128, BK=64, 512 threads (8 waves, 2M x 4N), per-wave out 128x32.
// LDS 96KB: 2 bufs x (A[256][64] | B[128][64]) bf16, (row&7)-XOR 16B swizzle,
// staged by gload_lds with pre-swizzled global source.
// Per K-tile t (buf b=t&1), 4 phases; quadrant order frees one half per phase:
//   ph0: read A0-frags+B0-frags; lgkm0; bar; stage B0(t+2); MFMA Q(0,0)
//   ph1: read B1-frags;          lgkm0; bar; stage A0(t+2); MFMA Q(0,1)
//   ph2: read A1-frags;          lgkm0; bar; stage B1(t+2); MFMA Q(1,1)
//   ph3: (B0 kept in regs)                    stage A1(t+2); MFMA Q(1,0)
//   tail: vmcnt(6) [= tile t+2's 6 in-flight loads] ; barrier
// Loads never drain to 0 in steady state (T3+T4); T5 setprio around MFMA.
template <int OUT_BF16, int SCALE_Q>
__global__ __launch_bounds__(512, 2) void gemm8p(
    const u16* __restrict__ A, const u16* __restrict__ Bt,
    const float* __restrict__ bias, void* __restrict__ C,
    int M, int N, int K) {
  __shared__ __align__(16) char smem[2][49152];  // [buf][A 32KB | B 16KB]
  int tid = threadIdx.x, w = tid >> 6, lane = tid & 63;
  int g = lane >> 4, l15 = lane & 15, l7 = lane & 7, l8 = lane >> 3;
  int wm = w >> 2, wn = w & 3;  // 2 x 4 wave grid
  int cpx = (int)gridDim.x >> 3;  // XCD-bijective swizzle (grid%8==0)
  int bid = (blockIdx.x & 7) * cpx + (blockIdx.x >> 3);
  int nblk = N >> 7;
  int bm = bid / nblk, bn = bid % nblk;
  int m0 = bm << 8, n0 = bn << 7;

  auto stageA = [&](int buf, int kt, int h) {  // A-half h: 128 rows, 2 gloads/wave
#pragma unroll
    for (int i = 0; i < 2; ++i) {
      int row = h * 128 + w * 16 + i * 8 + l8;
      const u16* src = A + (size_t)(m0 + row) * K + kt * 64 + 8 * (l7 ^ (row & 7));
      gload_lds16(src, &smem[buf][(h * 128 + w * 16 + i * 8) * 128]);
    }
  };
  auto stageB = [&](int buf, int kt, int h) {  // B-half h: 64 rows, 1 gload/wave
    int row = h * 64 + w * 8 + l8;
    const u16* src = Bt + (size_t)(n0 + row) * K + kt * 64 + 8 * (l7 ^ (row & 7));
    gload_lds16(src, &smem[buf][32768 + (h * 64 + w * 8) * 128]);
  };
  auto ldA = [&](int buf, int mh, int mi, int kk) -> bf16x8 {
    int row = mh * 128 + wm * 64 + mi * 16 + l15;
    return *(const bf16x8*)&smem[buf][row * 128 + (((kk * 4 + g) * 16) ^ ((row & 7) << 4))];
  };
  auto ldB = [&](int buf, int nh, int kk) -> bf16x8 {
    int row = nh * 64 + wn * 16 + l15;
    return *(const bf16x8*)&smem[buf][32768 + row * 128 + (((kk * 4 + g) * 16) ^ ((row & 7) << 4))];
  };

  f32x4 acc[2][4][2];  // [mh][mi][nh]
#pragma unroll
  for (int mh = 0; mh < 2; ++mh)
#pragma unroll
    for (int mi = 0; mi < 4; ++mi)
#pragma unroll
      for (int nh = 0; nh < 2; ++nh) acc[mh][mi][nh] = f32x4{0.f, 0.f, 0.f, 0.f};

  const int NT = K >> 6;
  // prologue: stage tiles 0 and 1 (6 loads each, per wave)
#pragma unroll
  for (int t = 0; t < 2; ++t) {
    stageB(t, t, 0); stageA(t, t, 0); stageB(t, t, 1); stageA(t, t, 1);
  }
  VMCNT6();  // own tile-0 loads landed
  __builtin_amdgcn_s_barrier();  // all waves' tile-0 loads landed

  for (int t = 0; t < NT; ++t) {
    int b = t & 1;
    bool pf = (t + 2) < NT;
    bf16x8 af[4][2], b0f[2], b1f[2];

    // ---- ph0: Q(0,0) ----
#pragma unroll
    for (int mi = 0; mi < 4; ++mi)
#pragma unroll
      for (int kk = 0; kk < 2; ++kk) af[mi][kk] = ldA(b, 0, mi, kk);
#pragma unroll
    for (int kk = 0; kk < 2; ++kk) b0f[kk] = ldB(b, 0, kk);
    LGKM0();
    __builtin_amdgcn_s_barrier();
    if (pf) stageB(b, t + 2, 0);
    __builtin_amdgcn_s_setprio(1);
#pragma unroll
    for (int mi = 0; mi < 4; ++mi)
#pragma unroll
      for (int kk = 0; kk < 2; ++kk)
        acc[0][mi][0] = __builtin_amdgcn_mfma_f32_16x16x32_bf16(af[mi][kk], b0f[kk], acc[0][mi][0], 0, 0, 0);
    __builtin_amdgcn_s_setprio(0);

    // ---- ph1: Q(0,1) ----
#pragma unroll
    for (int kk = 0; kk < 2; ++kk) b1f[kk] = ldB(b, 1, kk);
    LGKM0();
    __builtin_amdgcn_s_barrier();
    if (pf) stageA(b, t + 2, 0);
    __builtin_amdgcn_s_setprio(1);
#pragma unroll
    for (int mi = 0; mi < 4; ++mi)
#pragma unroll
      for (int kk = 0; kk < 2; ++kk)
        acc[0][mi][1] = __builtin_amdgcn_mfma_f32_16x16x32_bf16(af[mi][kk], b1f[kk], acc[0][mi][1], 0, 0, 0);
    __builtin_amdgcn_s_setprio(0);

    // ---- ph2: Q(1,1) ----
#pragma unroll
    for (int mi = 0; mi < 4; ++mi)
#pragma unroll
      for (int kk = 0; kk < 2; ++kk) af[mi][kk] = ldA(b, 1, mi, kk);
    LGKM0();
    __builtin_amdgcn_s_barrier();
    if (pf) stageB(b, t + 2, 1);
    __builtin_amdgcn_s_setprio(1);
#pragma unroll
    for (int mi = 0; mi < 4; ++mi)
#pragma unroll
      for (int kk = 0; kk < 2; ++kk)
        acc[1][mi][1] = __builtin_amdgcn_mfma_f32_16x16x32_bf16(af[mi][kk], b1f[kk], acc[1][mi][1], 0, 0, 0);
    __builtin_amdgcn_s_setprio(0);

    // ---- ph3: Q(1,0)  (A1 + retained B0 regs; no LDS reads) ----
    if (pf) stageA(b, t + 2, 1);
    __builtin_amdgcn_s_setprio(1);
#pragma unroll
    for (int mi = 0; mi < 4; ++mi)
#pragma unroll
      for (int kk = 0; kk < 2; ++kk)
        acc[1][mi][0] = __builtin_amdgcn_mfma_f32_16x16x32_bf16(af[mi][kk], b0f[kk], acc[1][mi][0], 0, 0, 0);
    __builtin_amdgcn_s_setprio(0);

    // ---- tail: counted drain + group barrier ----
    if (t < NT - 1) {
      if (pf) VMCNT6(); else VMCNT0();
      __builtin_amdgcn_s_barrier();
    }
  }

  // epilogue: D layout col=lane&15, row=(lane>>4)*4+r
#pragma unroll
  for (int nh = 0; nh < 2; ++nh) {
    int col = n0 + nh * 64 + wn * 16 + l15;
    float bv = bias[col];
    float sc = (SCALE_Q && col < 1024) ? 0.18033688011112042f : 1.0f;  // log2e/8
#pragma unroll
    for (int mh = 0; mh < 2; ++mh)
#pragma unroll
      for (int mi = 0; mi < 4; ++mi) {
        int rowb = m0 + mh * 128 + wm * 64 + mi * 16 + g * 4;
#pragma unroll
        for (int r = 0; r < 4; ++r) {
          float v = (acc[mh][mi][nh][r] + bv) * sc;
          if (OUT_BF16)
            ((u16*)C)[(size_t)(rowb + r) * N + col] = f2bf(v);
          else
            ((float*)C)[(size_t)(rowb + r) * N + col] = v;
        }
      }
  }
}

// ---------------------------------------------------------------------------
// Causal flash attention, swapped-QK^T (S^T in registers), in-register softmax
// in log2 domain (Q pre-scaled by 0.125*log2e in GEMM1), denominator via
// ones-MFMA, defer-max rescale (THR=8 log2 units -> P <= 256).
// qkv bf16 [B*S][3072]; head h owns 64 cols of each of q/k/v sections.
// Block = one (b,h) x 64 q-rows; 4 waves x 16 q-rows. KVBLK=64, double-buffered.

#if __has_builtin(__builtin_amdgcn_mfma_f32_16x16x16bf16_1k)
#define HAVE_MFMA16 1
__device__ __forceinline__ f32x4 mfma16(s16x4 a, s16x4 b, f32x4 c) {
  return __builtin_amdgcn_mfma_f32_16x16x16bf16_1k(a, b, c, 0, 0, 0);
}
#endif

struct V2reg { u16x8 a, b; };

__device__ __forceinline__ void stage_k(const u16* qb, char* kbuf, int kvt,
                                        int h, int w, int lane) {
  int l7 = lane & 7;
#pragma unroll
  for (int i = 0; i < 2; ++i) {
    int rbase = w * 16 + i * 8;
    int row = rbase + (lane >> 3);
    const u16* src = qb + (size_t)(kvt * 64 + row) * 3072 + 1024 + h * 64 + 8 * (l7 ^ (row & 7));
    gload_lds16(src, kbuf + rbase * 128);
  }
}

__device__ __forceinline__ V2reg load_v(const u16* qb, int kvt, int h, int kv0, int d0) {
  const u16* vs = qb + (size_t)(kvt * 64 + kv0) * 3072 + 2048 + h * 64 + d0;
  V2reg r;
  r.a = *(const u16x8*)vs;
  r.b = *(const u16x8*)(vs + 3072);
  return r;
}

__device__ __forceinline__ void write_v(char* vbuf, V2reg v, int kv0, int d0) {
#pragma unroll
  for (int j = 0; j < 8; ++j) {
    int d = d0 + j;
    u32 val = (u32)v.a[j] | ((u32)v.b[j] << 16);
    int sw = ((d & 7) ^ (d >> 3)) << 4;
    *(u32*)(vbuf + d * 128 + ((2 * kv0) ^ sw)) = val;
  }
}

__global__ __launch_bounds__(256, 4) void attn_fwd(
    const u16* __restrict__ qkv, u16* __restrict__ aout) {
  const int S = 2048, D3 = 3072;
  int bh = blockIdx.x & 63;
  int qt = 31 - (blockIdx.x >> 6);  // heavy tiles first
  int b = bh >> 4, h = bh & 15;
  const u16* qb = qkv + (size_t)b * S * D3;

  int tid = threadIdx.x;
  int w = tid >> 6, lane = tid & 63;
  int g = lane >> 4, l15 = lane & 15, l7 = lane & 7;

  __shared__ __align__(16) char Kb[2][8192];  // K [64 kv][64 d], (kv&7) swizzle
  __shared__ __align__(16) char Vb[2][8192];  // V^T [64 d][64 kv], ((d&7)^(d>>3)) swizzle

  // Q fragments (already scaled by log2e/8): rows qt*64+w*16+l15, k=ks*32+g*8+j
  int qrow = qt * 64 + w * 16 + l15;
  const u16* qp = qb + (size_t)qrow * D3 + h * 64 + g * 8;
  bf16x8 qf0 = *(const bf16x8*)qp;
  bf16x8 qf1 = *(const bf16x8*)(qp + 32);

  f32x4 oaT[4];  // O^T: col=q=l15, row d = db*16 + g*4 + r
#pragma unroll
  for (int i = 0; i < 4; ++i) oaT[i] = f32x4{0.f, 0.f, 0.f, 0.f};
  f32x4 l_acc = {0.f, 0.f, 0.f, 0.f};  // denominator (ones-MFMA); use [0]
  float m_s = -3e38f;

  int vkv0 = w * 16 + ((lane >> 3) << 1);
  int vd0 = l7 * 8;

  // prologue: stage tile 0
  stage_k(qb, Kb[0], 0, h, w, lane);
  {
    V2reg v = load_v(qb, 0, h, vkv0, vd0);
    write_v(Vb[0], v, vkv0, vd0);
  }
  __syncthreads();

  V2reg vreg;
  for (int kvt = 0; kvt <= qt; ++kvt) {
    int cur = kvt & 1;
    if (kvt < qt) {  // prefetch next tile while computing this one
      stage_k(qb, Kb[cur ^ 1], kvt + 1, h, w, lane);
      vreg = load_v(qb, kvt + 1, h, vkv0, vd0);
    }

    // QK^T swapped: sT[nb] = S^T tile (log2-scaled), col=q=l15, row=kv=nb*16+g*4+r
    f32x4 sT[4];
    __builtin_amdgcn_s_setprio(1);
#pragma unroll
    for (int nb = 0; nb < 4; ++nb) {
      int kv = nb * 16 + l15;
      const char* kb = Kb[cur] + kv * 128;
      int sw = (kv & 7) << 4;
      bf16x8 kf0 = *(const bf16x8*)(kb + ((g * 16) ^ sw));
      bf16x8 kf1 = *(const bf16x8*)(kb + ((64 + g * 16) ^ sw));
      f32x4 z = {0.f, 0.f, 0.f, 0.f};
      z = __builtin_amdgcn_mfma_f32_16x16x32_bf16(kf0, qf0, z, 0, 0, 0);
      z = __builtin_amdgcn_mfma_f32_16x16x32_bf16(kf1, qf1, z, 0, 0, 0);
      sT[nb] = z;
    }
    __builtin_amdgcn_s_setprio(0);

    // causal mask on diagonal tile (wave-uniform branch)
    if (kvt == qt) {
      int qloc = w * 16 + l15;
#pragma unroll
      for (int nb = 0; nb < 4; ++nb)
#pragma unroll
        for (int r = 0; r < 4; ++r)
          if (nb * 16 + g * 4 + r > qloc) sT[nb][r] = -1e30f;
    }

    // online softmax (log2 domain), defer-max
    float pm = -3e38f;
#pragma unroll
    for (int nb = 0; nb < 4; ++nb)
#pragma unroll
      for (int r = 0; r < 4; ++r) pm = fmaxf(pm, sT[nb][r]);
    pm = fmaxf(pm, __shfl_xor(pm, 16));
    pm = fmaxf(pm, __shfl_xor(pm, 32));
    if (!__all(pm - m_s <= 8.0f)) {
      float newm = fmaxf(m_s, pm);
      float corr = __builtin_amdgcn_exp2f(m_s - newm);
      m_s = newm;
      l_acc[0] *= corr;
#pragma unroll
      for (int db = 0; db < 4; ++db)
#pragma unroll
        for (int r = 0; r < 4; ++r) oaT[db][r] *= corr;
    }
#pragma unroll
    for (int nb = 0; nb < 4; ++nb)
#pragma unroll
      for (int r = 0; r < 4; ++r)
        sT[nb][r] = __builtin_amdgcn_exp2f(sT[nb][r] - m_s);

#ifdef HAVE_MFMA16
    // P^T fragments: lane holds P^T[kv=nb*16+g*4+j][q=l15] == B-operand of 16x16x16
    s16x4 pf[4];
#pragma unroll
    for (int nb = 0; nb < 4; ++nb) {
      bf16x4 t;
#pragma unroll
      for (int r = 0; r < 4; ++r) t[r] = (__bf16)sT[nb][r];
      pf[nb] = __builtin_bit_cast(s16x4, t);
    }
    s16x4 ones;
#pragma unroll
    for (int r = 0; r < 4; ++r) ones[r] = (short)0x3F80;  // bf16 1.0
    // PV: O^T[d][q] += V^T[d][kv] * P^T[kv][q]; denominator via ones-A MFMA
    __builtin_amdgcn_s_setprio(1);
#pragma unroll
    for (int nb = 0; nb < 4; ++nb) l_acc = mfma16(ones, pf[nb], l_acc);
#pragma unroll
    for (int db = 0; db < 4; ++db) {
      int d = db * 16 + l15;
      const char* vb = Vb[cur] + d * 128;
      int swd = ((d & 7) ^ (d >> 3)) << 4;
#pragma unroll
      for (int nb = 0; nb < 4; ++nb) {
        bf16x4 vf = *(const bf16x4*)(vb + ((nb * 32 + g * 8) ^ swd));
        oaT[db] = mfma16(__builtin_bit_cast(s16x4, vf), pf[nb], oaT[db]);
      }
    }
    __builtin_amdgcn_s_setprio(0);
#else
    // fallback: build x32 B-fragments via shfl exchange; denominator via ones-A
    u32 wlo[4], whi[4];
#pragma unroll
    for (int nb = 0; nb < 4; ++nb) {
      wlo[nb] = (u32)f2bf(sT[nb][0]) | ((u32)f2bf(sT[nb][1]) << 16);
      whi[nb] = (u32)f2bf(sT[nb][2]) | ((u32)f2bf(sT[nb][3]) << 16);
    }
    int srcA = (2 * (g & 1)) * 16 + l15;
    int srcB = srcA + 16;
    bool hi = (g >> 1) != 0;
    bf16x8 ones8;
#pragma unroll
    for (int j = 0; j < 8; ++j) ones8[j] = __builtin_bit_cast(__bf16, (u16)0x3F80);
    __builtin_amdgcn_s_setprio(1);
#pragma unroll
    for (int kb2 = 0; kb2 < 2; ++kb2) {
      int nbE = kb2 * 2, nbO = kb2 * 2 + 1;
      u32 a0 = __shfl(wlo[nbE], srcA), a1 = __shfl(whi[nbE], srcA);
      u32 a2 = __shfl(wlo[nbE], srcB), a3 = __shfl(whi[nbE], srcB);
      u32 b0 = __shfl(wlo[nbO], srcA), b1 = __shfl(whi[nbO], srcA);
      u32 b2 = __shfl(wlo[nbO], srcB), b3 = __shfl(whi[nbO], srcB);
      u32x4 ow = {hi ? b0 : a0, hi ? b1 : a1, hi ? b2 : a2, hi ? b3 : a3};
      bf16x8 pfrag = __builtin_bit_cast(bf16x8, ow);
      l_acc = __builtin_amdgcn_mfma_f32_16x16x32_bf16(ones8, pfrag, l_acc, 0, 0, 0);
#pragma unroll
      for (int db = 0; db < 4; ++db) {
        int d = db * 16 + l15;
        int swd = ((d & 7) ^ (d >> 3)) << 4;
        bf16x8 vf = *(const bf16x8*)(Vb[cur] + d * 128 + ((kb2 * 64 + g * 16) ^ swd));
        oaT[db] = __builtin_amdgcn_mfma_f32_16x16x32_bf16(vf, pfrag, oaT[db], 0, 0, 0);
      }
    }
    __builtin_amdgcn_s_setprio(0);
#endif

    if (kvt < qt) {
      write_v(Vb[cur ^ 1], vreg, vkv0, vd0);
      __syncthreads();
    }
  }

  // epilogue: lane owns q=l15; d = db*16 + g*4 + r
  float inv = 1.0f / l_acc[0];
  size_t obase = (size_t)(b * S + qt * 64 + w * 16 + l15) * 1024 + h * 64;
#pragma unroll
  for (int db = 0; db < 4; ++db) {
    ushort4 st;
    st.x = f2bf(oaT[db][0] * inv);
    st.y = f2bf(oaT[db][1] * inv);
    st.z = f2bf(oaT[db][2] * inv);
    st.w = f2bf(oaT[db][3] * inv);
    *(ushort4*)(aout + obase + db * 16 + g * 4) = st;
  }
}

// ---------------------------------------------------------------------------
extern "C" void kernel_launch(void* const* d_in, const int* in_sizes, int n_in,
                              void* d_out, int out_size, void* d_ws, size_t ws_size,
                              hipStream_t stream) {
  (void)in_sizes; (void)n_in; (void)out_size;
  const float* x     = (const float*)d_in[0];
  const float* w_in  = (const float*)d_in[1];
  const float* b_in  = (const float*)d_in[2];
  const float* w_out = (const float*)d_in[3];
  const float* b_out = (const float*)d_in[4];
  float* out = (float*)d_out;
  char* ws = (char*)d_ws;
  if (ws_size < 92274688u) return;  // need 88 MB

  u16* xb     = (u16*)(ws);                // bf16 x        [8192][1024] 16 MB
  u16* w_inT  = (u16*)(ws + (16u << 20));  // bf16 w_in^T   [3072][1024]  6 MB
  u16* w_outT = (u16*)(ws + (22u << 20));  // bf16 w_out^T  [1024][1024]  2 MB
  u16* qkv    = (u16*)(ws + (24u << 20));  // bf16 qkv      [8192][3072] 48 MB
  u16* aout   = (u16*)(ws + (72u << 20));  // bf16 attn out [8192][1024] 16 MB

  conv_f32_bf16<<<4096, 256, 0, stream>>>(x, xb, 1048576);
  conv_transpose<<<768, 256, 0, stream>>>(w_in, w_inT, 1024, 3072);
  conv_transpose<<<256, 256, 0, stream>>>(w_out, w_outT, 1024, 1024);
  gemm8p<1, 1><<<768, 512, 0, stream>>>(xb, w_inT, b_in, qkv, 8192, 3072, 1024);
  attn_fwd<<<2048, 256, 0, stream>>>(qkv, aout);
  gemm8p<0, 0><<<256, 512, 0, stream>>>(aout, w_outT, b_out, out, 8192, 1024, 1024);
}

// Round 6
// 257.147 us; speedup vs baseline: 1.0201x; 1.0201x over previous
//
#include <hip/hip_runtime.h>

typedef unsigned short u16;
typedef unsigned int   u32;
typedef float  f32x4  __attribute__((ext_vector_type(4)));
typedef __bf16 bf16x8 __attribute__((ext_vector_type(8)));
typedef __bf16 bf16x4 __attribute__((ext_vector_type(4)));
typedef short  s16x4  __attribute__((ext_vector_type(4)));
typedef unsigned short u16x8 __attribute__((ext_vector_type(8)));
typedef unsigned int   u32x4 __attribute__((ext_vector_type(4)));

// fp32 -> bf16 round-to-nearest-even
__device__ __forceinline__ u16 f2bf(float f) {
  u32 u = __builtin_bit_cast(u32, f);
  u = (u + 0x7fffu + ((u >> 16) & 1u)) >> 16;
  return (u16)u;
}

// async global->LDS, 16B per lane; LDS dest is wave-uniform base (HW adds lane*16)
__device__ __forceinline__ void gload_lds16(const void* g, void* l) {
  __builtin_amdgcn_global_load_lds(
      (const __attribute__((address_space(1))) void*)g,
      (__attribute__((address_space(3))) void*)l, 16, 0, 0);
}

#define VMCNT6() asm volatile("s_waitcnt vmcnt(6)" ::: "memory")
#define VMCNT0() asm volatile("s_waitcnt vmcnt(0)" ::: "memory")

// ---------------------------------------------------------------------------
// fp32 -> bf16 elementwise (8 elems/thread)
__global__ __launch_bounds__(256) void conv_f32_bf16(
    const float* __restrict__ in, u16* __restrict__ out, int n8) {
  int i = blockIdx.x * 256 + threadIdx.x;
  if (i >= n8) return;
  const float4* p = (const float4*)in;
  float4 a = p[2 * i], b = p[2 * i + 1];
  u16x8 r;
  r[0] = f2bf(a.x); r[1] = f2bf(a.y); r[2] = f2bf(a.z); r[3] = f2bf(a.w);
  r[4] = f2bf(b.x); r[5] = f2bf(b.y); r[6] = f2bf(b.z); r[7] = f2bf(b.w);
  ((u16x8*)out)[i] = r;
}

// fp32 [K][N] -> bf16 [N][K] transpose (64x64 tiles via LDS)
__global__ __launch_bounds__(256) void conv_transpose(
    const float* __restrict__ in, u16* __restrict__ out, int K, int N) {
  __shared__ float tile[64][65];
  int nb = N >> 6;
  int tk = blockIdx.x / nb, tn = blockIdx.x % nb;
  int t = threadIdx.x;
  int kl = t >> 4, n4 = (t & 15) * 4;
#pragma unroll
  for (int i = 0; i < 4; ++i) {
    int k = kl + 16 * i;
    float4 v = *(const float4*)(in + (size_t)(tk * 64 + k) * N + tn * 64 + n4);
    tile[k][n4] = v.x; tile[k][n4 + 1] = v.y; tile[k][n4 + 2] = v.z; tile[k][n4 + 3] = v.w;
  }
  __syncthreads();
  int nl = t >> 4, k4 = (t & 15) * 4;
#pragma unroll
  for (int i = 0; i < 4; ++i) {
    int n = nl + 16 * i;
    ushort4 o;
    o.x = f2bf(tile[k4 + 0][n]); o.y = f2bf(tile[k4 + 1][n]);
    o.z = f2bf(tile[k4 + 2][n]); o.w = f2bf(tile[k4 + 3][n]);
    *(ushort4*)(out + (size_t)(tn * 64 + n) * K + tk * 64 + k4) = o;
  }
}

// ---------------------------------------------------------------------------
// Triple-buffered counted-vmcnt GEMM: C[M][N] = A[M][K]*Bt[N][K]^T + bias.
// BM=256, BN=128, BK=64, 512 threads (8 waves, 2M x 4N), per-wave out 128x32.
// LDS 144KB: 3 bufs x (A[256][64] | B[128][64]) bf16, (row&7)-XOR 16B swizzle,
// staged by gload_lds with pre-swizzled global source.
// Tile t reads buf t%3; stages tile t+2 into buf (t+2)%3 — reader/writer bufs
// never alias, so NO intra-tile barriers or lgkm drains are needed. Per-tile
// sync is only: wave-local vmcnt(6) [tile t's 6 loads landed; 6 younger = t+1]
// then raw s_barrier [cross-wave landing + frees buf (t+2)%3 whose readers
// finished at t-1]. Loads never drain to 0 mid-loop (T4); compiler inserts
// fine-grained lgkmcnt for ds_read->MFMA (m97-verified). T5 setprio on MFMA.
template <int OUT_BF16, int SCALE_Q>
__global__ __launch_bounds__(512, 2) void gemm3b(
    const u16* __restrict__ A, const u16* __restrict__ Bt,
    const float* __restrict__ bias, void* __restrict__ C,
    int M, int N, int K) {
  __shared__ __align__(16) char smem[3][49152];  // [buf][A 32KB | B 16KB]
  int tid = threadIdx.x, w = tid >> 6, lane = tid & 63;
  int g = lane >> 4, l15 = lane & 15, l7 = lane & 7, l8 = lane >> 3;
  int wm = w >> 2, wn = w & 3;  // 2 x 4 wave grid
  int cpx = (int)gridDim.x >> 3;  // XCD-bijective swizzle (grid%8==0)
  int bid = (blockIdx.x & 7) * cpx + (blockIdx.x >> 3);
  int nblk = N >> 7;
  int bm = bid / nblk, bn = bid % nblk;
  int m0 = bm << 8, n0 = bn << 7;

  auto stageAB = [&](int buf, int kt) {  // 6 gloads/wave: full A (4) + full B (2)
#pragma unroll
    for (int i = 0; i < 4; ++i) {
      int row = w * 32 + i * 8 + l8;
      const u16* src = A + (size_t)(m0 + row) * K + kt * 64 + 8 * (l7 ^ (row & 7));
      gload_lds16(src, &smem[buf][(w * 32 + i * 8) * 128]);
    }
#pragma unroll
    for (int i = 0; i < 2; ++i) {
      int row = w * 16 + i * 8 + l8;
      const u16* src = Bt + (size_t)(n0 + row) * K + kt * 64 + 8 * (l7 ^ (row & 7));
      gload_lds16(src, &smem[buf][32768 + (w * 16 + i * 8) * 128]);
    }
  };
  auto ldA = [&](int buf, int mh, int mi, int kk) -> bf16x8 {
    int row = mh * 128 + wm * 64 + mi * 16 + l15;
    return *(const bf16x8*)&smem[buf][row * 128 + (((kk * 4 + g) * 16) ^ ((row & 7) << 4))];
  };
  auto ldB = [&](int buf, int ni, int kk) -> bf16x8 {
    int row = wn * 32 + ni * 16 + l15;
    return *(const bf16x8*)&smem[buf][32768 + row * 128 + (((kk * 4 + g) * 16) ^ ((row & 7) << 4))];
  };

  f32x4 acc[2][4][2];  // [mh][mi][ni]
#pragma unroll
  for (int mh = 0; mh < 2; ++mh)
#pragma unroll
    for (int mi = 0; mi < 4; ++mi)
#pragma unroll
      for (int ni = 0; ni < 2; ++ni) acc[mh][mi][ni] = f32x4{0.f, 0.f, 0.f, 0.f};

  const int NT = K >> 6;
  // prologue: stage tiles 0 (buf0) and 1 (buf1)
  stageAB(0, 0);
  stageAB(1, 1);

  int rb = 0;  // t % 3
  for (int t = 0; t < NT; ++t) {
    // tile-top sync: my tile-t loads landed (6 younger = t+1's), then cross-wave
    if (t < NT - 1) VMCNT6(); else VMCNT0();
    __builtin_amdgcn_s_barrier();
    if (t + 2 < NT) {
      int sb = rb + 2; if (sb >= 3) sb -= 3;
      stageAB(sb, t + 2);
    }

    bf16x8 af[4][2], b0f[2], b1f[2];
    // Q(0,0): A-half0 + B-col0
#pragma unroll
    for (int mi = 0; mi < 4; ++mi)
#pragma unroll
      for (int kk = 0; kk < 2; ++kk) af[mi][kk] = ldA(rb, 0, mi, kk);
#pragma unroll
    for (int kk = 0; kk < 2; ++kk) b0f[kk] = ldB(rb, 0, kk);
    __builtin_amdgcn_s_setprio(1);
#pragma unroll
    for (int mi = 0; mi < 4; ++mi)
#pragma unroll
      for (int kk = 0; kk < 2; ++kk)
        acc[0][mi][0] = __builtin_amdgcn_mfma_f32_16x16x32_bf16(af[mi][kk], b0f[kk], acc[0][mi][0], 0, 0, 0);
    __builtin_amdgcn_s_setprio(0);
    // Q(0,1): B-col1
#pragma unroll
    for (int kk = 0; kk < 2; ++kk) b1f[kk] = ldB(rb, 1, kk);
    __builtin_amdgcn_s_setprio(1);
#pragma unroll
    for (int mi = 0; mi < 4; ++mi)
#pragma unroll
      for (int kk = 0; kk < 2; ++kk)
        acc[0][mi][1] = __builtin_amdgcn_mfma_f32_16x16x32_bf16(af[mi][kk], b1f[kk], acc[0][mi][1], 0, 0, 0);
    __builtin_amdgcn_s_setprio(0);
    // Q(1,1): A-half1
#pragma unroll
    for (int mi = 0; mi < 4; ++mi)
#pragma unroll
      for (int kk = 0; kk < 2; ++kk) af[mi][kk] = ldA(rb, 1, mi, kk);
    __builtin_amdgcn_s_setprio(1);
#pragma unroll
    for (int mi = 0; mi < 4; ++mi)
#pragma unroll
      for (int kk = 0; kk < 2; ++kk)
        acc[1][mi][1] = __builtin_amdgcn_mfma_f32_16x16x32_bf16(af[mi][kk], b1f[kk], acc[1][mi][1], 0, 0, 0);
    __builtin_amdgcn_s_setprio(0);
    // Q(1,0): retained B-col0
    __builtin_amdgcn_s_setprio(1);
#pragma unroll
    for (int mi = 0; mi < 4; ++mi)
#pragma unroll
      for (int kk = 0; kk < 2; ++kk)
        acc[1][mi][0] = __builtin_amdgcn_mfma_f32_16x16x32_bf16(af[mi][kk], b0f[kk], acc[1][mi][0], 0, 0, 0);
    __builtin_amdgcn_s_setprio(0);

    ++rb; if (rb >= 3) rb -= 3;
  }

  // epilogue: D layout col=lane&15, row=(lane>>4)*4+r
#pragma unroll
  for (int ni = 0; ni < 2; ++ni) {
    int col = n0 + wn * 32 + ni * 16 + l15;
    float bv = bias[col];
    float sc = (SCALE_Q && col < 1024) ? 0.18033688011112042f : 1.0f;  // log2e/8
#pragma unroll
    for (int mh = 0; mh < 2; ++mh)
#pragma unroll
      for (int mi = 0; mi < 4; ++mi) {
        int rowb = m0 + mh * 128 + wm * 64 + mi * 16 + g * 4;
#pragma unroll
        for (int r = 0; r < 4; ++r) {
          float v = (acc[mh][mi][ni][r] + bv) * sc;
          if (OUT_BF16)
            ((u16*)C)[(size_t)(rowb + r) * N + col] = f2bf(v);
          else
            ((float*)C)[(size_t)(rowb + r) * N + col] = v;
        }
      }
  }
}

// ---------------------------------------------------------------------------
// Causal flash attention, swapped-QK^T (S^T in registers), in-register softmax
// in log2 domain (Q pre-scaled by 0.125*log2e in GEMM1), denominator via
// ones-MFMA, defer-max rescale (THR=8 log2 units -> P <= 256).
// qkv bf16 [B*S][3072]; head h owns 64 cols of each of q/k/v sections.
// Block = one (b,h) x 64 q-rows; 4 waves x 16 q-rows. KVBLK=64, double-buffered.

#if __has_builtin(__builtin_amdgcn_mfma_f32_16x16x16bf16_1k)
#define HAVE_MFMA16 1
__device__ __forceinline__ f32x4 mfma16(s16x4 a, s16x4 b, f32x4 c) {
  return __builtin_amdgcn_mfma_f32_16x16x16bf16_1k(a, b, c, 0, 0, 0);
}
#endif

struct V2reg { u16x8 a, b; };

__device__ __forceinline__ void stage_k(const u16* qb, char* kbuf, int kvt,
                                        int h, int w, int lane) {
  int l7 = lane & 7;
#pragma unroll
  for (int i = 0; i < 2; ++i) {
    int rbase = w * 16 + i * 8;
    int row = rbase + (lane >> 3);
    const u16* src = qb + (size_t)(kvt * 64 + row) * 3072 + 1024 + h * 64 + 8 * (l7 ^ (row & 7));
    gload_lds16(src, kbuf + rbase * 128);
  }
}

__device__ __forceinline__ V2reg load_v(const u16* qb, int kvt, int h, int kv0, int d0) {
  const u16* vs = qb + (size_t)(kvt * 64 + kv0) * 3072 + 2048 + h * 64 + d0;
  V2reg r;
  r.a = *(const u16x8*)vs;
  r.b = *(const u16x8*)(vs + 3072);
  return r;
}

__device__ __forceinline__ void write_v(char* vbuf, V2reg v, int kv0, int d0) {
#pragma unroll
  for (int j = 0; j < 8; ++j) {
    int d = d0 + j;
    u32 val = (u32)v.a[j] | ((u32)v.b[j] << 16);
    int sw = ((d & 7) ^ (d >> 3)) << 4;
    *(u32*)(vbuf + d * 128 + ((2 * kv0) ^ sw)) = val;
  }
}

__global__ __launch_bounds__(256, 4) void attn_fwd(
    const u16* __restrict__ qkv, u16* __restrict__ aout) {
  const int S = 2048, D3 = 3072;
  int bh = blockIdx.x & 63;
  int qt = 31 - (blockIdx.x >> 6);  // heavy tiles first
  int b = bh >> 4, h = bh & 15;
  const u16* qb = qkv + (size_t)b * S * D3;

  int tid = threadIdx.x;
  int w = tid >> 6, lane = tid & 63;
  int g = lane >> 4, l15 = lane & 15, l7 = lane & 7;

  __shared__ __align__(16) char Kb[2][8192];  // K [64 kv][64 d], (kv&7) swizzle
  __shared__ __align__(16) char Vb[2][8192];  // V^T [64 d][64 kv], ((d&7)^(d>>3)) swizzle

  // Q fragments (already scaled by log2e/8): rows qt*64+w*16+l15, k=ks*32+g*8+j
  int qrow = qt * 64 + w * 16 + l15;
  const u16* qp = qb + (size_t)qrow * D3 + h * 64 + g * 8;
  bf16x8 qf0 = *(const bf16x8*)qp;
  bf16x8 qf1 = *(const bf16x8*)(qp + 32);

  f32x4 oaT[4];  // O^T: col=q=l15, row d = db*16 + g*4 + r
#pragma unroll
  for (int i = 0; i < 4; ++i) oaT[i] = f32x4{0.f, 0.f, 0.f, 0.f};
  f32x4 l_acc = {0.f, 0.f, 0.f, 0.f};  // denominator (ones-MFMA); use [0]
  float m_s = -3e38f;

  int vkv0 = w * 16 + ((lane >> 3) << 1);
  int vd0 = l7 * 8;

  // prologue: stage tile 0
  stage_k(qb, Kb[0], 0, h, w, lane);
  {
    V2reg v = load_v(qb, 0, h, vkv0, vd0);
    write_v(Vb[0], v, vkv0, vd0);
  }
  __syncthreads();

  V2reg vreg;
  for (int kvt = 0; kvt <= qt; ++kvt) {
    int cur = kvt & 1;
    if (kvt < qt) {  // prefetch next tile while computing this one
      stage_k(qb, Kb[cur ^ 1], kvt + 1, h, w, lane);
      vreg = load_v(qb, kvt + 1, h, vkv0, vd0);
    }

    // QK^T swapped: sT[nb] = S^T tile (log2-scaled), col=q=l15, row=kv=nb*16+g*4+r
    f32x4 sT[4];
    __builtin_amdgcn_s_setprio(1);
#pragma unroll
    for (int nb = 0; nb < 4; ++nb) {
      int kv = nb * 16 + l15;
      const char* kb = Kb[cur] + kv * 128;
      int sw = (kv & 7) << 4;
      bf16x8 kf0 = *(const bf16x8*)(kb + ((g * 16) ^ sw));
      bf16x8 kf1 = *(const bf16x8*)(kb + ((64 + g * 16) ^ sw));
      f32x4 z = {0.f, 0.f, 0.f, 0.f};
      z = __builtin_amdgcn_mfma_f32_16x16x32_bf16(kf0, qf0, z, 0, 0, 0);
      z = __builtin_amdgcn_mfma_f32_16x16x32_bf16(kf1, qf1, z, 0, 0, 0);
      sT[nb] = z;
    }
    __builtin_amdgcn_s_setprio(0);

    // causal mask on diagonal tile (wave-uniform branch)
    if (kvt == qt) {
      int qloc = w * 16 + l15;
#pragma unroll
      for (int nb = 0; nb < 4; ++nb)
#pragma unroll
        for (int r = 0; r < 4; ++r)
          if (nb * 16 + g * 4 + r > qloc) sT[nb][r] = -1e30f;
    }

    // online softmax (log2 domain), defer-max
    float pm = -3e38f;
#pragma unroll
    for (int nb = 0; nb < 4; ++nb)
#pragma unroll
      for (int r = 0; r < 4; ++r) pm = fmaxf(pm, sT[nb][r]);
    pm = fmaxf(pm, __shfl_xor(pm, 16));
    pm = fmaxf(pm, __shfl_xor(pm, 32));
    if (!__all(pm - m_s <= 8.0f)) {
      float newm = fmaxf(m_s, pm);
      float corr = __builtin_amdgcn_exp2f(m_s - newm);
      m_s = newm;
      l_acc[0] *= corr;
#pragma unroll
      for (int db = 0; db < 4; ++db)
#pragma unroll
        for (int r = 0; r < 4; ++r) oaT[db][r] *= corr;
    }
#pragma unroll
    for (int nb = 0; nb < 4; ++nb)
#pragma unroll
      for (int r = 0; r < 4; ++r)
        sT[nb][r] = __builtin_amdgcn_exp2f(sT[nb][r] - m_s);

#ifdef HAVE_MFMA16
    // P^T fragments: lane holds P^T[kv=nb*16+g*4+j][q=l15] == B-operand of 16x16x16
    s16x4 pf[4];
#pragma unroll
    for (int nb = 0; nb < 4; ++nb) {
      bf16x4 t;
#pragma unroll
      for (int r = 0; r < 4; ++r) t[r] = (__bf16)sT[nb][r];
      pf[nb] = __builtin_bit_cast(s16x4, t);
    }
    s16x4 ones;
#pragma unroll
    for (int r = 0; r < 4; ++r) ones[r] = (short)0x3F80;  // bf16 1.0
    // PV: O^T[d][q] += V^T[d][kv] * P^T[kv][q]; denominator via ones-A MFMA
    __builtin_amdgcn_s_setprio(1);
#pragma unroll
    for (int nb = 0; nb < 4; ++nb) l_acc = mfma16(ones, pf[nb], l_acc);
#pragma unroll
    for (int db = 0; db < 4; ++db) {
      int d = db * 16 + l15;
      const char* vb = Vb[cur] + d * 128;
      int swd = ((d & 7) ^ (d >> 3)) << 4;
#pragma unroll
      for (int nb = 0; nb < 4; ++nb) {
        bf16x4 vf = *(const bf16x4*)(vb + ((nb * 32 + g * 8) ^ swd));
        oaT[db] = mfma16(__builtin_bit_cast(s16x4, vf), pf[nb], oaT[db]);
      }
    }
    __builtin_amdgcn_s_setprio(0);
#else
    // fallback: build x32 B-fragments via shfl exchange; denominator via ones-A
    u32 wlo[4], whi[4];
#pragma unroll
    for (int nb = 0; nb < 4; ++nb) {
      wlo[nb] = (u32)f2bf(sT[nb][0]) | ((u32)f2bf(sT[nb][1]) << 16);
      whi[nb] = (u32)f2bf(sT[nb][2]) | ((u32)f2bf(sT[nb][3]) << 16);
    }
    int srcA = (2 * (g & 1)) * 16 + l15;
    int srcB = srcA + 16;
    bool hi = (g >> 1) != 0;
    bf16x8 ones8;
#pragma unroll
    for (int j = 0; j < 8; ++j) ones8[j] = __builtin_bit_cast(__bf16, (u16)0x3F80);
    __builtin_amdgcn_s_setprio(1);
#pragma unroll
    for (int kb2 = 0; kb2 < 2; ++kb2) {
      int nbE = kb2 * 2, nbO = kb2 * 2 + 1;
      u32 a0 = __shfl(wlo[nbE], srcA), a1 = __shfl(whi[nbE], srcA);
      u32 a2 = __shfl(wlo[nbE], srcB), a3 = __shfl(whi[nbE], srcB);
      u32 b0 = __shfl(wlo[nbO], srcA), b1 = __shfl(whi[nbO], srcA);
      u32 b2 = __shfl(wlo[nbO], srcB), b3 = __shfl(whi[nbO], srcB);
      u32x4 ow = {hi ? b0 : a0, hi ? b1 : a1, hi ? b2 : a2, hi ? b3 : a3};
      bf16x8 pfrag = __builtin_bit_cast(bf16x8, ow);
      l_acc = __builtin_amdgcn_mfma_f32_16x16x32_bf16(ones8, pfrag, l_acc, 0, 0, 0);
#pragma unroll
      for (int db = 0; db < 4; ++db) {
        int d = db * 16 + l15;
        int swd = ((d & 7) ^ (d >> 3)) << 4;
        bf16x8 vf = *(const bf16x8*)(Vb[cur] + d * 128 + ((kb2 * 64 + g * 16) ^ swd));
        oaT[db] = __builtin_amdgcn_mfma_f32_16x16x32_bf16(vf, pfrag, oaT[db], 0, 0, 0);
      }
    }
    __builtin_amdgcn_s_setprio(0);
#endif

    if (kvt < qt) {
      write_v(Vb[cur ^ 1], vreg, vkv0, vd0);
      __syncthreads();
    }
  }

  // epilogue: lane owns q=l15; d = db*16 + g*4 + r
  float inv = 1.0f / l_acc[0];
  size_t obase = (size_t)(b * S + qt * 64 + w * 16 + l15) * 1024 + h * 64;
#pragma unroll
  for (int db = 0; db < 4; ++db) {
    ushort4 st;
    st.x = f2bf(oaT[db][0] * inv);
    st.y = f2bf(oaT[db][1] * inv);
    st.z = f2bf(oaT[db][2] * inv);
    st.w = f2bf(oaT[db][3] * inv);
    *(ushort4*)(aout + obase + db * 16 + g * 4) = st;
  }
}

// ---------------------------------------------------------------------------
extern "C" void kernel_launch(void* const* d_in, const int* in_sizes, int n_in,
                              void* d_out, int out_size, void* d_ws, size_t ws_size,
                              hipStream_t stream) {
  (void)in_sizes; (void)n_in; (void)out_size;
  const float* x     = (const float*)d_in[0];
  const float* w_in  = (const float*)d_in[1];
  const float* b_in  = (const float*)d_in[2];
  const float* w_out = (const float*)d_in[3];
  const float* b_out = (const float*)d_in[4];
  float* out = (float*)d_out;
  char* ws = (char*)d_ws;
  if (ws_size < 92274688u) return;  // need 88 MB

  u16* xb     = (u16*)(ws);                // bf16 x        [8192][1024] 16 MB
  u16* w_inT  = (u16*)(ws + (16u << 20));  // bf16 w_in^T   [3072][1024]  6 MB
  u16* w_outT = (u16*)(ws + (22u << 20));  // bf16 w_out^T  [1024][1024]  2 MB
  u16* qkv    = (u16*)(ws + (24u << 20));  // bf16 qkv      [8192][3072] 48 MB
  u16* aout   = (u16*)(ws + (72u << 20));  // bf16 attn out [8192][1024] 16 MB

  conv_f32_bf16<<<4096, 256, 0, stream>>>(x, xb, 1048576);
  conv_transpose<<<768, 256, 0, stream>>>(w_in, w_inT, 1024, 3072);
  conv_transpose<<<256, 256, 0, stream>>>(w_out, w_outT, 1024, 1024);
  gemm3b<1, 1><<<768, 512, 0, stream>>>(xb, w_inT, b_in, qkv, 8192, 3072, 1024);
  attn_fwd<<<2048, 256, 0, stream>>>(qkv, aout);
  gemm3b<0, 0><<<256, 512, 0, stream>>>(aout, w_outT, b_out, out, 8192, 1024, 1024);
}